// Round 1
// 2549.000 us; speedup vs baseline: 1.5301x; 1.5301x over previous
//
#include <hip/hip_runtime.h>
#include <hip/hip_bf16.h>

#define HIDDEN 4096
#define INTER  11008
#define TOKENS 8192

typedef __bf16 bf16x8 __attribute__((ext_vector_type(8)));
typedef float  f32x4  __attribute__((ext_vector_type(4)));

typedef unsigned int as1_uint __attribute__((address_space(1)));
typedef unsigned int as3_uint __attribute__((address_space(3)));

// async global->LDS, 16B per lane; LDS dest is wave-uniform base + lane*16
__device__ __forceinline__ void gld_lds16(const void* g, void* l) {
    __builtin_amdgcn_global_load_lds((as1_uint*)g, (as3_uint*)l, 16, 0, 0);
}

__device__ __forceinline__ unsigned short f2bf_bits(float f) {
    union { float f; unsigned u; } c; c.f = f;
    unsigned u = c.u;
    u += 0x7fffu + ((u >> 16) & 1u);   // round-to-nearest-even
    return (unsigned short)(u >> 16);
}

__global__ __launch_bounds__(256) void cast_f32_bf16(const float4* __restrict__ in,
                                                     ushort4* __restrict__ out, long n4) {
    long i = (long)blockIdx.x * blockDim.x + threadIdx.x;
    long stride = (long)gridDim.x * blockDim.x;
    for (; i < n4; i += stride) {
        float4 v = in[i];
        ushort4 o;
        o.x = f2bf_bits(v.x); o.y = f2bf_bits(v.y);
        o.z = f2bf_bits(v.z); o.w = f2bf_bits(v.w);
        out[i] = o;
    }
}

// ---------------------------------------------------------------------------
// 256x256 8-phase GEMM (HK-schedule port, per the verified m201 template).
// C = A @ B^T, A[M][KD], B[N][KD] row-major bf16.
// 512 threads = 8 waves (2 M x 4 N), per-wave output 128x64, BK=64.
// LDS 128 KiB dynamic: A at 0 (2 bufs x 32KB), B at 64KB (2 bufs x 32KB).
// Row = 128 B; swizzle: 16B-slot ^= (row&7)  (write side pre-swizzles the
// GLOBAL source address; global_load_lds dest stays linear — rule #21).
// GATEUP: B-tile interleaves Wg (even LDS rows) / Wu (odd rows); epilogue
// pairs g/u across adjacent lanes via shfl_xor(1) and writes H = silu(g)*u.
// ---------------------------------------------------------------------------
template<bool GATEUP>
__global__ __launch_bounds__(512, 2)
void gemm8(const __hip_bfloat16* __restrict__ A,
           const __hip_bfloat16* __restrict__ B0,
           const __hip_bfloat16* __restrict__ B1,
           void* __restrict__ Cout)
{
    constexpr int KD    = GATEUP ? HIDDEN : INTER;
    constexpr int NT    = KD / 64;   // K-tiles
    constexpr int NITER = NT / 2;    // 2 K-tiles per iteration

    extern __shared__ char lds[];

    const int tid  = threadIdx.x;
    const int wave = tid >> 6;
    const int lane = tid & 63;
    const int wm   = wave >> 2;      // 0..1
    const int wn   = wave & 3;       // 0..3
    const int ml   = lane & 15;
    const int kg   = lane >> 4;      // 0..3
    const int swzr = (ml & 7) << 4;  // read-side XOR (row&7 == ml&7 for frag rows)

    // T1: bijective XCD-contiguous remap (nwg % 8 == 0), then m-fastest.
    const int nwg = (int)gridDim.x;
    int wg = (int)blockIdx.x;
    wg = (wg & 7) * (nwg >> 3) + (wg >> 3);
    const int mb = wg & 31;          // TOKENS/256 == 32, m-fastest
    const int nb = wg >> 5;
    const int m0 = mb * 256;

    // staging coords: thread t covers LDS linear bytes t*16 (+ 8192 for round 1)
    const int rg = tid >> 3;                        // row-in-half (round 0)
    const int sl = ((tid & 7) ^ (rg & 7)) * 8;      // pre-swizzled source k-slot (elems)

    auto stageA = [&](int buf, int half, int kt) {
        const __hip_bfloat16* s0 = A + (long)(m0 + half * 128 + rg) * KD + kt * 64 + sl;
        char* d = lds + buf * 32768 + half * 16384 + wave * 1024;
        gld_lds16(s0, d);                 // rows 0..63 of half
        gld_lds16(s0 + 64 * KD, d + 8192); // rows 64..127 (same swizzle: +64 ≡ 0 mod 8)
    };
    auto stageB = [&](int buf, int half, int kt) {
        char* d = lds + 65536 + buf * 32768 + half * 16384 + wave * 1024;
        if constexpr (GATEUP) {
            // LDS B row rb = half*128 + rg (+64): even rb -> Wg, odd -> Wu, n = nb*128 + rb/2
            const __hip_bfloat16* base = (rg & 1) ? B1 : B0;
            const __hip_bfloat16* s0 = base + (long)(nb * 128 + half * 64 + (rg >> 1)) * KD + kt * 64 + sl;
            gld_lds16(s0, d);
            gld_lds16(s0 + 32 * KD, d + 8192);
        } else {
            const __hip_bfloat16* s0 = B0 + (long)(nb * 256 + half * 128 + rg) * KD + kt * 64 + sl;
            gld_lds16(s0, d);
            gld_lds16(s0 + 64 * KD, d + 8192);
        }
    };

    f32x4 acc[8][4];
#pragma unroll
    for (int i = 0; i < 8; ++i)
#pragma unroll
        for (int j = 0; j < 4; ++j) acc[i][j] = f32x4{0.f, 0.f, 0.f, 0.f};

    bf16x8 a[4][2], b[2][2];

    // prologue: tile0 -> buf0 (A0,A1,B0,B1), tile1 A-half0 -> buf1 ("phase 8" of iter -1)
    stageA(0, 0, 0); stageA(0, 1, 0); stageB(0, 0, 0); stageB(0, 1, 0);
    stageA(1, 0, 1);
    asm volatile("s_waitcnt vmcnt(2)" ::: "memory");  // tile0 landed; tile1-A0 in flight
    __builtin_amdgcn_s_barrier();

#define LDA_BODY(BUF, MH) \
    _Pragma("unroll") \
    for (int m = 0; m < 4; ++m) { \
        const char* pa = lds + (BUF) * 32768 + (wm * 128 + (MH) * 64 + m * 16 + ml) * 128; \
        a[m][0] = *(const bf16x8*)(pa + ((kg * 16) ^ swzr)); \
        a[m][1] = *(const bf16x8*)(pa + ((64 + kg * 16) ^ swzr)); \
    }
#define LDB_BODY(BUF, NH) \
    _Pragma("unroll") \
    for (int n = 0; n < 2; ++n) { \
        const char* pb = lds + 65536 + (BUF) * 32768 + (wn * 64 + (NH) * 32 + n * 16 + ml) * 128; \
        b[n][0] = *(const bf16x8*)(pb + ((kg * 16) ^ swzr)); \
        b[n][1] = *(const bf16x8*)(pb + ((64 + kg * 16) ^ swzr)); \
    }
#define MFMA_BODY(MH, NH) \
    _Pragma("unroll") \
    for (int m = 0; m < 4; ++m) { \
        _Pragma("unroll") \
        for (int n = 0; n < 2; ++n) { \
            f32x4& c = acc[(MH) * 4 + m][(NH) * 2 + n]; \
            c = __builtin_amdgcn_mfma_f32_16x16x32_bf16(a[m][0], b[n][0], c, 0, 0, 0); \
            c = __builtin_amdgcn_mfma_f32_16x16x32_bf16(a[m][1], b[n][1], c, 0, 0, 0); \
        } \
    }
#define PHASE(BUF, MH, NH, DOA, DOB, STG, VMW) \
    { \
        if (DOA) { LDA_BODY(BUF, MH) } \
        if (DOB) { LDB_BODY(BUF, NH) } \
        STG; \
        __builtin_amdgcn_s_barrier(); \
        asm volatile("s_waitcnt lgkmcnt(0)" ::: "memory"); \
        __builtin_amdgcn_s_setprio(1); \
        MFMA_BODY(MH, NH) \
        __builtin_amdgcn_s_setprio(0); \
        if (VMW) { asm volatile("s_waitcnt vmcnt(2)" ::: "memory"); } \
        __builtin_amdgcn_s_barrier(); \
    }

    // Stage mapping (race-free: each phase stages a half-tile whose last reader
    // finished at the previous phase's end-barrier):
    //   p1: t1 A1->buf1   p2: t1 B0->buf1   p3: t1 B1->buf1   p4: t2 A0->buf0 +vmcnt(2)
    //   p5: t2 A1->buf0   p6: t2 B0->buf0   p7: t2 B1->buf0   p8: t3 A0->buf1 +vmcnt(2)
    // vmcnt(2) leaves exactly the current phase's 2 loads in flight; the 8 older
    // loads (= the K-tile consumed next) are guaranteed landed before its reads.
    for (int i = 0; i < NITER; ++i) {
        const int t1 = 2 * i + 1;
        int t2 = 2 * i + 2; if (t2 >= NT) t2 -= NT;  // wrap: staged-but-unread
        int t3 = 2 * i + 3; if (t3 >= NT) t3 -= NT;
        PHASE(0, 0, 0, 1, 1, stageA(1, 1, t1), 0)   // Q(0,0): 12 ds_reads
        PHASE(0, 0, 1, 0, 1, stageB(1, 0, t1), 0)   // Q(0,1): 4
        PHASE(0, 1, 1, 1, 0, stageB(1, 1, t1), 0)   // Q(1,1): 8
        PHASE(0, 1, 0, 0, 1, stageA(0, 0, t2), 1)   // Q(1,0): 4 (b reload)
        PHASE(1, 0, 0, 1, 1, stageA(0, 1, t2), 0)
        PHASE(1, 0, 1, 0, 1, stageB(0, 0, t2), 0)
        PHASE(1, 1, 1, 1, 0, stageB(0, 1, t2), 0)
        PHASE(1, 1, 0, 0, 1, stageA(1, 0, t3), 1)
    }
#undef PHASE
#undef MFMA_BODY
#undef LDB_BODY
#undef LDA_BODY

    // epilogue. C/D layout: col=lane&15, row=(lane>>4)*4+reg (verified mapping).
    if constexpr (GATEUP) {
        __hip_bfloat16* H = (__hip_bfloat16*)Cout;
        const int r0 = (lane & 1) * 2;   // even lane stores rows r=0,1; odd r=2,3
#pragma unroll
        for (int m8 = 0; m8 < 8; ++m8) {
#pragma unroll
            for (int n4 = 0; n4 < 4; ++n4) {
                f32x4 v = acc[m8][n4];
                float h[4];
#pragma unroll
                for (int r = 0; r < 4; ++r) {
                    float o = __shfl_xor(v[r], 1);      // partner in (g,u) lane pair
                    float g = (lane & 1) ? o : v[r];
                    float u = (lane & 1) ? v[r] : o;
                    h[r] = g / (1.f + __expf(-g)) * u;  // silu(g)*u (dup across pair)
                }
                float sa = (lane & 1) ? h[2] : h[0];
                float sb = (lane & 1) ? h[3] : h[1];
                const long row  = m0 + wm * 128 + m8 * 16 + kg * 4 + r0;
                const int  hcol = nb * 128 + wn * 32 + n4 * 8 + (ml >> 1);
                H[row * (long)INTER + hcol]       = __float2bfloat16(sa);
                H[(row + 1) * (long)INTER + hcol] = __float2bfloat16(sb);
            }
        }
    } else {
        float* O = (float*)Cout;
#pragma unroll
        for (int m8 = 0; m8 < 8; ++m8) {
#pragma unroll
            for (int n4 = 0; n4 < 4; ++n4) {
                const long row = m0 + wm * 128 + m8 * 16 + kg * 4;
                const int  col = nb * 256 + wn * 64 + n4 * 16 + ml;
#pragma unroll
                for (int r = 0; r < 4; ++r)
                    O[(row + r) * (long)HIDDEN + col] = acc[m8][n4][r];
            }
        }
    }
}

extern "C" void kernel_launch(void* const* d_in, const int* in_sizes, int n_in,
                              void* d_out, int out_size, void* d_ws, size_t ws_size,
                              hipStream_t stream) {
    const float* x  = (const float*)d_in[0];   // [TOKENS][HIDDEN]
    const float* wg = (const float*)d_in[1];   // [INTER][HIDDEN]
    const float* wu = (const float*)d_in[2];   // [INTER][HIDDEN]
    const float* wd = (const float*)d_in[3];   // [HIDDEN][INTER]
    float* out = (float*)d_out;                // [TOKENS][HIDDEN]

    // workspace layout (peak 427.8 MB):
    //   [0, SZ_H)                         hidden bf16
    //   [SZ_H, SZ_H+SZ_X)                 x bf16
    //   [SZ_H+SZ_X, +SZ_W)                Wg bf16
    //   [SZ_H+SZ_X+SZ_W, +SZ_W)           Wu bf16
    //   Wd bf16 aliases [SZ_H, SZ_H+SZ_W) (x/Wg dead after gateup; stream-ordered)
    const size_t SZ_H = (size_t)TOKENS * INTER * 2;   // 180,355,072
    const size_t SZ_X = (size_t)TOKENS * HIDDEN * 2;  //  67,108,864
    const size_t SZ_W = (size_t)INTER * HIDDEN * 2;   //  90,177,536

    char* ws = (char*)d_ws;
    __hip_bfloat16* Hb  = (__hip_bfloat16*)(ws);
    __hip_bfloat16* Xb  = (__hip_bfloat16*)(ws + SZ_H);
    __hip_bfloat16* Wgb = (__hip_bfloat16*)(ws + SZ_H + SZ_X);
    __hip_bfloat16* Wub = (__hip_bfloat16*)(ws + SZ_H + SZ_X + SZ_W);
    __hip_bfloat16* Wdb = (__hip_bfloat16*)(ws + SZ_H);  // alias, used after gateup

    static bool attr_set = false;
    if (!attr_set) {
        (void)hipFuncSetAttribute(reinterpret_cast<const void*>(&gemm8<true>),
                                  hipFuncAttributeMaxDynamicSharedMemorySize, 131072);
        (void)hipFuncSetAttribute(reinterpret_cast<const void*>(&gemm8<false>),
                                  hipFuncAttributeMaxDynamicSharedMemorySize, 131072);
        attr_set = true;
    }

    auto cast_launch = [&](const float* src, __hip_bfloat16* dst, long n) {
        long n4 = n >> 2;
        long b = (n4 + 255) / 256;
        if (b > 16384) b = 16384;
        cast_f32_bf16<<<(int)b, 256, 0, stream>>>((const float4*)src, (ushort4*)dst, n4);
    };

    cast_launch(x,  Xb,  (long)TOKENS * HIDDEN);
    cast_launch(wg, Wgb, (long)INTER * HIDDEN);
    cast_launch(wu, Wub, (long)INTER * HIDDEN);

    // grid: n-blocks x m-blocks, 1D, m-fastest after XCD remap.
    // gateup: (11008/128)*(8192/256) = 86*32 = 2752 (%8==0)
    gemm8<true><<<dim3((INTER / 128) * (TOKENS / 256)), 512, 131072, stream>>>(Xb, Wgb, Wub, Hb);

    cast_launch(wd, Wdb, (long)HIDDEN * INTER);

    // down: (4096/256)*(8192/256) = 16*32 = 512 (%8==0)
    gemm8<false><<<dim3((HIDDEN / 256) * (TOKENS / 256)), 512, 131072, stream>>>(Hb, Wdb, nullptr, out);
}